// Round 4
// baseline (322.339 us; speedup 1.0000x reference)
//
#include <hip/hip_runtime.h>

// B=8, S=256, C=256, V=64 — fp32 in/out, split-fp16 MFMA internally.
// out[b,s,z,k] = tanh( BIL + r[b,z,k] + t[b,s,k] )
//   W_eff[i,j,k] = W[i,j,k] + (i==j)*linmul_w[k,j]   (split wt_hi+wt_lo, n'=k*256+j)
//   ctx split: ch_hi + ch_lo (exact fp16 pair)
//   GEMM1 (one loop, 3 planes): tmp = Ah·Bh + Al·Bh + Ah·Bl   (fp32 acc, fp16 store)
//   GEMM2 (one loop, 2 planes): BIL = tmp ⊗ (Ch + Cl)  [tmp as MFMA-A, ctx as MFMA-B
//     so D reg-dim = (s,k) -> float4 k-contiguous output stores]
//   error ≈ tmp-fp16 rounding only → absmax ~0.011 (R3-calibrated)

typedef __attribute__((ext_vector_type(8))) _Float16 half8;
typedef __attribute__((ext_vector_type(4))) _Float16 half4v;
typedef __attribute__((ext_vector_type(4))) float f32x4;

__device__ __forceinline__ void async16(const void* g, void* l) {
  __builtin_amdgcn_global_load_lds(
      (__attribute__((address_space(1))) void*)g,
      (__attribute__((address_space(3))) void*)l, 16, 0, 0);
}

// ---- merged prep: blocks [0,512): r/t vectors + ctx split; [512,768): W_eff split ----
__global__ __launch_bounds__(256) void prep(
    const float* __restrict__ ctx, const float* __restrict__ W,
    const float* __restrict__ bias, const float* __restrict__ l1w,
    const float* __restrict__ l1b, const float* __restrict__ l2w,
    const float* __restrict__ l2b, const float* __restrict__ lmw,
    const float* __restrict__ lmb, const float* __restrict__ ldw,
    const float* __restrict__ ldb, float* __restrict__ rbuf,
    float* __restrict__ tbuf, _Float16* __restrict__ ch_hi,
    _Float16* __restrict__ ch_lo, _Float16* __restrict__ wt_hi,
    _Float16* __restrict__ wt_lo) {
  __shared__ float SH[256 * 68];  // prep_wt: [i][k] fp32 pad 64->68; prep_rt: first 1024
  const int t = threadIdx.x;
  if (blockIdx.x < 512) {
    float* Cs = SH;
    const int row0 = blockIdx.x * 4;
    float4 v = ((const float4*)(ctx + (size_t)row0 * 256))[t];
    ((float4*)Cs)[t] = v;
    {
      float xs[4] = {v.x, v.y, v.z, v.w};
      half4v h, l;
#pragma unroll
      for (int e = 0; e < 4; ++e) {
        _Float16 hh = (_Float16)xs[e];
        h[e] = hh;
        l[e] = (_Float16)(xs[e] - (float)hh);
      }
      *(half4v*)&ch_hi[(size_t)row0 * 256 + t * 4] = h;
      *(half4v*)&ch_lo[(size_t)row0 * 256 + t * 4] = l;
    }
    __syncthreads();
    const int k = t & 63, lr = t >> 6;
    const float* l1r = l1w + k * 256;
    const float* l2r = l2w + k * 256;
    const float* ldr = ldw + k * 256;
    float a1 = 0.f, a2 = 0.f;
    for (int c = 0; c < 256; c += 4) {
      float4 w1 = *(const float4*)(l1r + c);
      float4 w2 = *(const float4*)(l2r + c);
      float4 wd = *(const float4*)(ldr + c);
      float4 cv = *(const float4*)(&Cs[lr * 256 + c]);
      a1 += cv.x * (w1.x + wd.x) + cv.y * (w1.y + wd.y) +
            cv.z * (w1.z + wd.z) + cv.w * (w1.w + wd.w);
      a2 += cv.x * (w2.x - wd.x) + cv.y * (w2.y - wd.y) +
            cv.z * (w2.z - wd.z) + cv.w * (w2.w - wd.w);
    }
    int row = row0 + lr;
    rbuf[row * 64 + k] = a1 + l1b[k];
    tbuf[row * 64 + k] = a2 + l2b[k] + bias[k] + lmb[k] + ldb[k];
  } else {
    float* T = SH;
    const int j = blockIdx.x - 512;
#pragma unroll
    for (int p = 0; p < 16; ++p) {
      int i = p * 16 + (t >> 4);
      int c = t & 15;
      float4 v = *(const float4*)&W[(size_t)i * 16384 + j * 64 + c * 4];
      if (i == j) {
        v.x += lmw[(c * 4 + 0) * 256 + j];
        v.y += lmw[(c * 4 + 1) * 256 + j];
        v.z += lmw[(c * 4 + 2) * 256 + j];
        v.w += lmw[(c * 4 + 3) * 256 + j];
      }
      *(float4*)&T[i * 68 + c * 4] = v;
    }
    __syncthreads();
    const int k = t >> 2, i0 = (t & 3) * 64;
    _Float16* dh = wt_hi + ((size_t)(k * 256 + j)) * 256 + i0;
    _Float16* dl = wt_lo + ((size_t)(k * 256 + j)) * 256 + i0;
#pragma unroll
    for (int u = 0; u < 64; u += 8) {
      half8 h, l;
#pragma unroll
      for (int e = 0; e < 8; ++e) {
        float x = T[(i0 + u + e) * 68 + k];
        _Float16 hh = (_Float16)x;
        h[e] = hh;
        l[e] = (_Float16)(x - (float)hh);
      }
      *(half8*)(dh + u) = h;
      *(half8*)(dl + u) = l;
    }
  }
}

// ---- GEMM1: tmp[m][n'] (M=2048,N=16384,K=256), 3 planes in one loop ----
__global__ __launch_bounds__(256) void gemm1(const _Float16* __restrict__ ahp,
                                             const _Float16* __restrict__ alp,
                                             const _Float16* __restrict__ bhp,
                                             const _Float16* __restrict__ blp,
                                             _Float16* __restrict__ tmp) {
  __shared__ _Float16 Ah[128 * 32];
  __shared__ _Float16 Al[128 * 32];
  __shared__ _Float16 Bh[128 * 32];
  __shared__ _Float16 Bl[128 * 32];
  const int t = threadIdx.x;
  const int lane = t & 63, wave = t >> 6;
  const int m0 = blockIdx.y * 128, n0 = blockIdx.x * 128;
  const int wm = (wave & 1) * 64, wn = (wave >> 1) * 64;
  const int r = lane & 15, q = lane >> 4;
  f32x4 acc[4][4] = {};
  const int row = t >> 2, seg = (t & 3) * 8;
  const _Float16* gAh = ahp + (size_t)(m0 + row) * 256 + seg;
  const _Float16* gAl = alp + (size_t)(m0 + row) * 256 + seg;
  const _Float16* gBh = bhp + (size_t)(n0 + row) * 256 + seg;
  const _Float16* gBl = blp + (size_t)(n0 + row) * 256 + seg;
  for (int k0 = 0; k0 < 256; k0 += 32) {
    async16(gAh + k0, &Ah[t * 8]);
    async16(gAh + 64 * 256 + k0, &Ah[2048 + t * 8]);
    async16(gAl + k0, &Al[t * 8]);
    async16(gAl + 64 * 256 + k0, &Al[2048 + t * 8]);
    async16(gBh + k0, &Bh[t * 8]);
    async16(gBh + 64 * 256 + k0, &Bh[2048 + t * 8]);
    async16(gBl + k0, &Bl[t * 8]);
    async16(gBl + 64 * 256 + k0, &Bl[2048 + t * 8]);
    __syncthreads();
    half8 a[4], c[4], bh[4], bl[4];
#pragma unroll
    for (int mi = 0; mi < 4; ++mi) {
      a[mi] = *(const half8*)&Ah[(wm + mi * 16 + r) * 32 + q * 8];
      c[mi] = *(const half8*)&Al[(wm + mi * 16 + r) * 32 + q * 8];
    }
#pragma unroll
    for (int ni = 0; ni < 4; ++ni) {
      bh[ni] = *(const half8*)&Bh[(wn + ni * 16 + r) * 32 + q * 8];
      bl[ni] = *(const half8*)&Bl[(wn + ni * 16 + r) * 32 + q * 8];
    }
#pragma unroll
    for (int mi = 0; mi < 4; ++mi)
#pragma unroll
      for (int ni = 0; ni < 4; ++ni) {
        acc[mi][ni] = __builtin_amdgcn_mfma_f32_16x16x32_f16(a[mi], bh[ni],
                                                             acc[mi][ni], 0, 0, 0);
        acc[mi][ni] = __builtin_amdgcn_mfma_f32_16x16x32_f16(c[mi], bh[ni],
                                                             acc[mi][ni], 0, 0, 0);
        acc[mi][ni] = __builtin_amdgcn_mfma_f32_16x16x32_f16(a[mi], bl[ni],
                                                             acc[mi][ni], 0, 0, 0);
      }
    __syncthreads();
  }
#pragma unroll
  for (int mi = 0; mi < 4; ++mi)
#pragma unroll
    for (int ni = 0; ni < 4; ++ni) {
      int m = m0 + wm + mi * 16 + q * 4;
      int n = n0 + wn + ni * 16 + r;
#pragma unroll
      for (int e = 0; e < 4; ++e)
        tmp[(size_t)(m + e) * 16384 + n] = (_Float16)acc[mi][ni][e];
    }
}

// ---- GEMM2 + epilogue: block = (b, s-quad, 128(n)x128(z) subtile) ----
// MFMA-A = tmp rows (n=(s_l,k)), MFMA-B = ctx planes (z). D reg-dim = n -> k-contig.
__global__ __launch_bounds__(256) void gemm2(const _Float16* __restrict__ ahp,
                                             const _Float16* __restrict__ alp,
                                             const _Float16* __restrict__ tmp,
                                             const float* __restrict__ rbuf,
                                             const float* __restrict__ tbuf,
                                             float* __restrict__ out) {
  __shared__ _Float16 Ch[128 * 32];  // ctx_b hi [z][j-chunk]
  __shared__ _Float16 Cl[128 * 32];  // ctx_b lo
  __shared__ _Float16 Ts[128 * 32];  // tmp rows [n][j-chunk]
  const int t = threadIdx.x;
  const int lane = t & 63, wave = t >> 6;
  const int gx = blockIdx.x;
  const int bq = gx >> 2, mt = (gx >> 1) & 1, nt = gx & 1;
  const int b = bq >> 6, s0 = (bq & 63) * 4;
  const int wn = (wave & 1) * 64, wz = (wave >> 1) * 64;
  const int r = lane & 15, q = lane >> 4;
  f32x4 acc[4][4] = {};  // [fi over n][fj over z]
  const int row = t >> 2, seg = (t & 3) * 8;
  const _Float16* gCh = ahp + ((size_t)b * 256 + mt * 128 + row) * 256 + seg;
  const _Float16* gCl = alp + ((size_t)b * 256 + mt * 128 + row) * 256 + seg;
  const _Float16* gT =
      tmp + ((size_t)(b * 256 + s0) * 64 + nt * 128 + row) * 256 + seg;
  for (int j0 = 0; j0 < 256; j0 += 32) {
    async16(gCh + j0, &Ch[t * 8]);
    async16(gCh + 64 * 256 + j0, &Ch[2048 + t * 8]);
    async16(gCl + j0, &Cl[t * 8]);
    async16(gCl + 64 * 256 + j0, &Cl[2048 + t * 8]);
    async16(gT + j0, &Ts[t * 8]);
    async16(gT + 64 * 256 + j0, &Ts[2048 + t * 8]);
    __syncthreads();
    half8 tf[4], chf[4], clf[4];
#pragma unroll
    for (int fi = 0; fi < 4; ++fi)
      tf[fi] = *(const half8*)&Ts[(wn + fi * 16 + r) * 32 + q * 8];
#pragma unroll
    for (int fj = 0; fj < 4; ++fj) {
      chf[fj] = *(const half8*)&Ch[(wz + fj * 16 + r) * 32 + q * 8];
      clf[fj] = *(const half8*)&Cl[(wz + fj * 16 + r) * 32 + q * 8];
    }
#pragma unroll
    for (int fi = 0; fi < 4; ++fi)
#pragma unroll
      for (int fj = 0; fj < 4; ++fj) {
        acc[fi][fj] = __builtin_amdgcn_mfma_f32_16x16x32_f16(tf[fi], chf[fj],
                                                             acc[fi][fj], 0, 0, 0);
        acc[fi][fj] = __builtin_amdgcn_mfma_f32_16x16x32_f16(tf[fi], clf[fj],
                                                             acc[fi][fj], 0, 0, 0);
      }
    __syncthreads();
  }
#pragma unroll
  for (int fi = 0; fi < 4; ++fi)
#pragma unroll
    for (int fj = 0; fj < 4; ++fj) {
      int n_l = wn + fi * 16 + q * 4;           // within 128-tile
      int kb = n_l & 63;                        // k base (mult of 4)
      int s_l = nt * 2 + (n_l >> 6);
      int z = mt * 128 + wz + fj * 16 + r;
      float4 rv = *(const float4*)&rbuf[(size_t)b * 16384 + z * 64 + kb];
      float4 tv = *(const float4*)&tbuf[(b * 256 + s0 + s_l) * 64 + kb];
      float xs[4] = {acc[fi][fj][0] + rv.x + tv.x, acc[fi][fj][1] + rv.y + tv.y,
                     acc[fi][fj][2] + rv.z + tv.z, acc[fi][fj][3] + rv.w + tv.w};
      float4 o;
      float* op = &o.x;
#pragma unroll
      for (int e = 0; e < 4; ++e) {
        float ax = fabsf(xs[e]);
        float ev = __expf(-2.0f * ax);
        float y = (1.0f - ev) / (1.0f + ev);
        op[e] = copysignf(y, xs[e]);
      }
      *(float4*)&out[(((size_t)b * 256 + s0 + s_l) * 256 + z) * 64 + kb] = o;
    }
}

extern "C" void kernel_launch(void* const* d_in, const int* in_sizes, int n_in,
                              void* d_out, int out_size, void* d_ws, size_t ws_size,
                              hipStream_t stream) {
  const float* ctx  = (const float*)d_in[0];
  const float* W    = (const float*)d_in[1];
  const float* bias = (const float*)d_in[2];
  const float* l1w  = (const float*)d_in[3];
  const float* l1b  = (const float*)d_in[4];
  const float* l2w  = (const float*)d_in[5];
  const float* l2b  = (const float*)d_in[6];
  const float* lmw  = (const float*)d_in[7];
  const float* lmb  = (const float*)d_in[8];
  const float* ldw  = (const float*)d_in[9];
  const float* ldb  = (const float*)d_in[10];
  float* out = (float*)d_out;

  char* ws = (char*)d_ws;
  _Float16* ch_hi = (_Float16*)ws;                         // 1 MiB
  _Float16* ch_lo = (_Float16*)(ws + (1u << 20));          // 1 MiB
  _Float16* wt_hi = (_Float16*)(ws + (2u << 20));          // 8 MiB
  _Float16* wt_lo = (_Float16*)(ws + (10u << 20));         // 8 MiB
  _Float16* tmp   = (_Float16*)(ws + (18u << 20));         // 64 MiB
  float* rbuf = (float*)(ws + (82u << 20));                // 512 KiB
  float* tbuf = rbuf + 2048 * 64;                          // 512 KiB

  prep<<<768, 256, 0, stream>>>(ctx, W, bias, l1w, l1b, l2w, l2b, lmw, lmb, ldw,
                                ldb, rbuf, tbuf, ch_hi, ch_lo, wt_hi, wt_lo);
  gemm1<<<dim3(128, 16), 256, 0, stream>>>(ch_hi, ch_lo, wt_hi, wt_lo, tmp);
  gemm2<<<2048, 256, 0, stream>>>(ch_hi, ch_lo, tmp, rbuf, tbuf, out);
}

// Round 5
// 299.227 us; speedup vs baseline: 1.0772x; 1.0772x over previous
//
#include <hip/hip_runtime.h>

// B=8, S=256, C=256, V=64 — fp32 in/out, split-fp16 MFMA internally.
// out[b,s,z,k] = tanh( Σ_j T'[s][k][j]·ctx[z][j] + t'[s,k] )
//   W_eff[i,j,k] = W[i,j,k] + (i==j)*linmul_w[k,j]   (split wt_hi+wt_lo, n'=k*256+j)
//   T'[(b,s)][k][j] = Σ_i ctx·W_eff + (l1w+ldw)[k,j]   <- r folded into tmp (GEMM1)
//   t'[s,k] = ctx_s·(l2w-ldw) + l1b+l2b+bias+lmb+ldb
//   GEMM1: 3 planes (Ah·Bh + Al·Bh + Ah·Bl), fp32 acc, +w1d, fp16 store
//   GEMM2: 2 planes (T'·Ch + T'·Cl), epilogue = +t', cheap tanh
//   error ≈ tmp-fp16 rounding only → absmax ~0.011 (R3/R4-calibrated)

typedef __attribute__((ext_vector_type(8))) _Float16 half8;
typedef __attribute__((ext_vector_type(4))) _Float16 half4v;
typedef __attribute__((ext_vector_type(4))) float f32x4;

__device__ __forceinline__ void async16(const void* g, void* l) {
  __builtin_amdgcn_global_load_lds(
      (__attribute__((address_space(1))) void*)g,
      (__attribute__((address_space(3))) void*)l, 16, 0, 0);
}

__device__ __forceinline__ float fast_tanh(float x) {
  // tanh(x) = 1 - 2/(1+e^{2x}); exact at both tails, err ~1e-6
  float tt = __builtin_amdgcn_exp2f(x * 2.885390082f);
  return fmaf(-2.0f, __builtin_amdgcn_rcpf(tt + 1.0f), 1.0f);
}

// ---- merged prep ----
// blocks [0,512): t' vector + ctx hi/lo split
// blocks [512,768): W_eff hi/lo split (n'-major)
// block 768: w1d = l1w + ldw (elementwise fp32)
__global__ __launch_bounds__(256) void prep(
    const float* __restrict__ ctx, const float* __restrict__ W,
    const float* __restrict__ bias, const float* __restrict__ l1w,
    const float* __restrict__ l1b, const float* __restrict__ l2w,
    const float* __restrict__ l2b, const float* __restrict__ lmw,
    const float* __restrict__ lmb, const float* __restrict__ ldw,
    const float* __restrict__ ldb, float* __restrict__ w1d,
    float* __restrict__ tbuf, _Float16* __restrict__ ch_hi,
    _Float16* __restrict__ ch_lo, _Float16* __restrict__ wt_hi,
    _Float16* __restrict__ wt_lo) {
  __shared__ float SH[256 * 68];
  const int t = threadIdx.x;
  if (blockIdx.x < 512) {
    float* Cs = SH;
    const int row0 = blockIdx.x * 4;
    float4 v = ((const float4*)(ctx + (size_t)row0 * 256))[t];
    ((float4*)Cs)[t] = v;
    {
      float xs[4] = {v.x, v.y, v.z, v.w};
      half4v h, l;
#pragma unroll
      for (int e = 0; e < 4; ++e) {
        _Float16 hh = (_Float16)xs[e];
        h[e] = hh;
        l[e] = (_Float16)(xs[e] - (float)hh);
      }
      *(half4v*)&ch_hi[(size_t)row0 * 256 + t * 4] = h;
      *(half4v*)&ch_lo[(size_t)row0 * 256 + t * 4] = l;
    }
    __syncthreads();
    const int k = t & 63, lr = t >> 6;
    const float* l2r = l2w + k * 256;
    const float* ldr = ldw + k * 256;
    float a2 = 0.f;
    for (int c = 0; c < 256; c += 4) {
      float4 w2 = *(const float4*)(l2r + c);
      float4 wd = *(const float4*)(ldr + c);
      float4 cv = *(const float4*)(&Cs[lr * 256 + c]);
      a2 += cv.x * (w2.x - wd.x) + cv.y * (w2.y - wd.y) +
            cv.z * (w2.z - wd.z) + cv.w * (w2.w - wd.w);
    }
    int row = row0 + lr;
    tbuf[row * 64 + k] =
        a2 + l1b[k] + l2b[k] + bias[k] + lmb[k] + ldb[k];
  } else if (blockIdx.x < 768) {
    float* T = SH;
    const int j = blockIdx.x - 512;
#pragma unroll
    for (int p = 0; p < 16; ++p) {
      int i = p * 16 + (t >> 4);
      int c = t & 15;
      float4 v = *(const float4*)&W[(size_t)i * 16384 + j * 64 + c * 4];
      if (i == j) {
        v.x += lmw[(c * 4 + 0) * 256 + j];
        v.y += lmw[(c * 4 + 1) * 256 + j];
        v.z += lmw[(c * 4 + 2) * 256 + j];
        v.w += lmw[(c * 4 + 3) * 256 + j];
      }
      *(float4*)&T[i * 68 + c * 4] = v;
    }
    __syncthreads();
    const int k = t >> 2, i0 = (t & 3) * 64;
    _Float16* dh = wt_hi + ((size_t)(k * 256 + j)) * 256 + i0;
    _Float16* dl = wt_lo + ((size_t)(k * 256 + j)) * 256 + i0;
#pragma unroll
    for (int u = 0; u < 64; u += 8) {
      half8 h, l;
#pragma unroll
      for (int e = 0; e < 8; ++e) {
        float x = T[(i0 + u + e) * 68 + k];
        _Float16 hh = (_Float16)x;
        h[e] = hh;
        l[e] = (_Float16)(x - (float)hh);
      }
      *(half8*)(dh + u) = h;
      *(half8*)(dl + u) = l;
    }
  } else {
    // w1d[n'=k*256+j] = l1w[k][j] + ldw[k][j] — both are [V][C] row-major = [n']
    const float4* a4 = (const float4*)l1w;
    const float4* b4 = (const float4*)ldw;
    float4* o4 = (float4*)w1d;
#pragma unroll
    for (int u = 0; u < 16; ++u) {
      int idx = u * 256 + t;
      float4 x = a4[idx], y = b4[idx];
      float4 o;
      o.x = x.x + y.x; o.y = x.y + y.y; o.z = x.z + y.z; o.w = x.w + y.w;
      o4[idx] = o;
    }
  }
}

// ---- GEMM1: tmp[m][n'] = ctx·W_eff + w1d  (M=2048,N=16384,K=256) ----
// grid 512 = (mgrp 4) x (n-tile 128); each block does 4 m-tiles (B L2-reuse,
// same-n blocks are 128 apart -> same XCD).
__global__ __launch_bounds__(256) void gemm1(const _Float16* __restrict__ ahp,
                                             const _Float16* __restrict__ alp,
                                             const _Float16* __restrict__ bhp,
                                             const _Float16* __restrict__ blp,
                                             const float* __restrict__ w1d,
                                             _Float16* __restrict__ tmp) {
  __shared__ _Float16 Ah[128 * 32];
  __shared__ _Float16 Al[128 * 32];
  __shared__ _Float16 Bh[128 * 32];
  __shared__ _Float16 Bl[128 * 32];
  const int t = threadIdx.x;
  const int lane = t & 63, wave = t >> 6;
  const int n0 = (blockIdx.x & 127) * 128;
  const int mgrp = blockIdx.x >> 7;
  const int wm = (wave & 1) * 64, wn = (wave >> 1) * 64;
  const int r = lane & 15, q = lane >> 4;
  const int row = t >> 2, seg = (t & 3) * 8;
  const _Float16* gBh = bhp + (size_t)(n0 + row) * 256 + seg;
  const _Float16* gBl = blp + (size_t)(n0 + row) * 256 + seg;
  float w1dv[4];
#pragma unroll
  for (int ni = 0; ni < 4; ++ni) w1dv[ni] = w1d[n0 + wn + ni * 16 + r];
  for (int it = 0; it < 4; ++it) {
    const int m0 = (mgrp * 4 + it) * 128;
    const _Float16* gAh = ahp + (size_t)(m0 + row) * 256 + seg;
    const _Float16* gAl = alp + (size_t)(m0 + row) * 256 + seg;
    f32x4 acc[4][4] = {};
    for (int k0 = 0; k0 < 256; k0 += 32) {
      async16(gAh + k0, &Ah[t * 8]);
      async16(gAh + 64 * 256 + k0, &Ah[2048 + t * 8]);
      async16(gAl + k0, &Al[t * 8]);
      async16(gAl + 64 * 256 + k0, &Al[2048 + t * 8]);
      async16(gBh + k0, &Bh[t * 8]);
      async16(gBh + 64 * 256 + k0, &Bh[2048 + t * 8]);
      async16(gBl + k0, &Bl[t * 8]);
      async16(gBl + 64 * 256 + k0, &Bl[2048 + t * 8]);
      __syncthreads();
      half8 a[4], c[4], bh[4], bl[4];
#pragma unroll
      for (int mi = 0; mi < 4; ++mi) {
        a[mi] = *(const half8*)&Ah[(wm + mi * 16 + r) * 32 + q * 8];
        c[mi] = *(const half8*)&Al[(wm + mi * 16 + r) * 32 + q * 8];
      }
#pragma unroll
      for (int ni = 0; ni < 4; ++ni) {
        bh[ni] = *(const half8*)&Bh[(wn + ni * 16 + r) * 32 + q * 8];
        bl[ni] = *(const half8*)&Bl[(wn + ni * 16 + r) * 32 + q * 8];
      }
#pragma unroll
      for (int mi = 0; mi < 4; ++mi)
#pragma unroll
        for (int ni = 0; ni < 4; ++ni) {
          acc[mi][ni] = __builtin_amdgcn_mfma_f32_16x16x32_f16(
              a[mi], bh[ni], acc[mi][ni], 0, 0, 0);
          acc[mi][ni] = __builtin_amdgcn_mfma_f32_16x16x32_f16(
              c[mi], bh[ni], acc[mi][ni], 0, 0, 0);
          acc[mi][ni] = __builtin_amdgcn_mfma_f32_16x16x32_f16(
              a[mi], bl[ni], acc[mi][ni], 0, 0, 0);
        }
      __syncthreads();
    }
#pragma unroll
    for (int mi = 0; mi < 4; ++mi)
#pragma unroll
      for (int ni = 0; ni < 4; ++ni) {
        int m = m0 + wm + mi * 16 + q * 4;
        int n = n0 + wn + ni * 16 + r;
#pragma unroll
        for (int e = 0; e < 4; ++e)
          tmp[(size_t)(m + e) * 16384 + n] =
              (_Float16)(acc[mi][ni][e] + w1dv[ni]);
      }
  }
}

// ---- GEMM2 + epilogue: gx = tile(mt,nt)*512 + bq  (same-bq -> same XCD) ----
__global__ __launch_bounds__(256) void gemm2(const _Float16* __restrict__ ahp,
                                             const _Float16* __restrict__ alp,
                                             const _Float16* __restrict__ tmp,
                                             const float* __restrict__ tbuf,
                                             float* __restrict__ out) {
  __shared__ _Float16 Ch[128 * 32];  // ctx_b hi [z][j-chunk]
  __shared__ _Float16 Cl[128 * 32];  // ctx_b lo
  __shared__ _Float16 Ts[128 * 32];  // tmp rows [n][j-chunk]
  const int t = threadIdx.x;
  const int lane = t & 63, wave = t >> 6;
  const int gx = blockIdx.x;
  const int bq = gx & 511, tile = gx >> 9;
  const int mt = tile >> 1, nt = tile & 1;
  const int b = bq >> 6, s0 = (bq & 63) * 4;
  const int wn = (wave & 1) * 64, wz = (wave >> 1) * 64;
  const int r = lane & 15, q = lane >> 4;
  f32x4 acc[4][4] = {};  // [fi over n][fj over z]
  const int row = t >> 2, seg = (t & 3) * 8;
  const _Float16* gCh = ahp + ((size_t)b * 256 + mt * 128 + row) * 256 + seg;
  const _Float16* gCl = alp + ((size_t)b * 256 + mt * 128 + row) * 256 + seg;
  const _Float16* gT =
      tmp + ((size_t)(b * 256 + s0) * 64 + nt * 128 + row) * 256 + seg;
  for (int j0 = 0; j0 < 256; j0 += 32) {
    async16(gCh + j0, &Ch[t * 8]);
    async16(gCh + 64 * 256 + j0, &Ch[2048 + t * 8]);
    async16(gCl + j0, &Cl[t * 8]);
    async16(gCl + 64 * 256 + j0, &Cl[2048 + t * 8]);
    async16(gT + j0, &Ts[t * 8]);
    async16(gT + 64 * 256 + j0, &Ts[2048 + t * 8]);
    __syncthreads();
    half8 tf[4], chf[4], clf[4];
#pragma unroll
    for (int fi = 0; fi < 4; ++fi)
      tf[fi] = *(const half8*)&Ts[(wn + fi * 16 + r) * 32 + q * 8];
#pragma unroll
    for (int fj = 0; fj < 4; ++fj) {
      chf[fj] = *(const half8*)&Ch[(wz + fj * 16 + r) * 32 + q * 8];
      clf[fj] = *(const half8*)&Cl[(wz + fj * 16 + r) * 32 + q * 8];
    }
#pragma unroll
    for (int fi = 0; fi < 4; ++fi)
#pragma unroll
      for (int fj = 0; fj < 4; ++fj) {
        acc[fi][fj] = __builtin_amdgcn_mfma_f32_16x16x32_f16(
            tf[fi], chf[fj], acc[fi][fj], 0, 0, 0);
        acc[fi][fj] = __builtin_amdgcn_mfma_f32_16x16x32_f16(
            tf[fi], clf[fj], acc[fi][fj], 0, 0, 0);
      }
    __syncthreads();
  }
  // epilogue: +t', cheap tanh; fj outer / fi inner so the 4 stores of each
  // 256-B output row are adjacent (write combining)
  float4 tv[4];
  int kb_[4], sl_[4];
#pragma unroll
  for (int fi = 0; fi < 4; ++fi) {
    int n_l = wn + fi * 16 + q * 4;
    kb_[fi] = n_l & 63;
    sl_[fi] = nt * 2 + (n_l >> 6);
    tv[fi] = *(const float4*)&tbuf[(b * 256 + s0 + sl_[fi]) * 64 + kb_[fi]];
  }
#pragma unroll
  for (int fj = 0; fj < 4; ++fj) {
    int z = mt * 128 + wz + fj * 16 + r;
#pragma unroll
    for (int fi = 0; fi < 4; ++fi) {
      float xs[4] = {acc[fi][fj][0] + tv[fi].x, acc[fi][fj][1] + tv[fi].y,
                     acc[fi][fj][2] + tv[fi].z, acc[fi][fj][3] + tv[fi].w};
      float4 o;
      o.x = fast_tanh(xs[0]);
      o.y = fast_tanh(xs[1]);
      o.z = fast_tanh(xs[2]);
      o.w = fast_tanh(xs[3]);
      *(float4*)&out[(((size_t)b * 256 + s0 + sl_[fi]) * 256 + z) * 64 +
                     kb_[fi]] = o;
    }
  }
}

extern "C" void kernel_launch(void* const* d_in, const int* in_sizes, int n_in,
                              void* d_out, int out_size, void* d_ws, size_t ws_size,
                              hipStream_t stream) {
  const float* ctx  = (const float*)d_in[0];
  const float* W    = (const float*)d_in[1];
  const float* bias = (const float*)d_in[2];
  const float* l1w  = (const float*)d_in[3];
  const float* l1b  = (const float*)d_in[4];
  const float* l2w  = (const float*)d_in[5];
  const float* l2b  = (const float*)d_in[6];
  const float* lmw  = (const float*)d_in[7];
  const float* lmb  = (const float*)d_in[8];
  const float* ldw  = (const float*)d_in[9];
  const float* ldb  = (const float*)d_in[10];
  float* out = (float*)d_out;

  char* ws = (char*)d_ws;
  _Float16* ch_hi = (_Float16*)ws;                         // 1 MiB
  _Float16* ch_lo = (_Float16*)(ws + (1u << 20));          // 1 MiB
  _Float16* wt_hi = (_Float16*)(ws + (2u << 20));          // 8 MiB
  _Float16* wt_lo = (_Float16*)(ws + (10u << 20));         // 8 MiB
  _Float16* tmp   = (_Float16*)(ws + (18u << 20));         // 64 MiB
  float* w1d  = (float*)(ws + (82u << 20));                // 64 KiB
  float* tbuf = (float*)(ws + (83u << 20));                // 512 KiB

  prep<<<769, 256, 0, stream>>>(ctx, W, bias, l1w, l1b, l2w, l2b, lmw, lmb, ldw,
                                ldb, w1d, tbuf, ch_hi, ch_lo, wt_hi, wt_lo);
  gemm1<<<512, 256, 0, stream>>>(ch_hi, ch_lo, wt_hi, wt_lo, w1d, tmp);
  gemm2<<<2048, 256, 0, stream>>>(ch_hi, ch_lo, tmp, tbuf, out);
}